// Round 2
// baseline (1259.170 us; speedup 1.0000x reference)
//
#include <hip/hip_runtime.h>
#include <stdint.h>

// ISTA_Net fused MFMA implementation for gfx950.  Round 2: 16-wave blocks,
// channel-split waves (waves 0-7 = ch0, 8-15 = ch1) -> 4 waves/SIMD.
// Shapes: M=1024, N=128, K=256, T=10, BATCH=8192. LAMBD=1.
// Inputs: y(8192,2,128) W(2,128,256) WX(2,256,128) E0(2,1024,256) etas(11) gammas(11)
// Outputs: x_T(2,8192,256) ++ loss_sparse ++ loss_eq/T ++ out_sparse  (4194307 floats)

typedef short s8v __attribute__((ext_vector_type(8)));   // 8 bf16 (4 VGPRs) MFMA operand
typedef short s4v __attribute__((ext_vector_type(4)));
typedef float f16v __attribute__((ext_vector_type(16))); // 32x32 MFMA accumulator

#define MFMA(a, b, c) __builtin_amdgcn_mfma_f32_32x32x16_bf16((a), (b), (c), 0, 0, 0)

__device__ __forceinline__ short f2bf(float f) {
  uint32_t u = __builtin_bit_cast(uint32_t, f);
  u = (u + 0x7FFFu + ((u >> 16) & 1u)) >> 16;   // RNE
  return (short)u;
}

// ---------------- prep kernels ----------------

__global__ void zero_tail(float* out) {
  if (threadIdx.x < 3) out[4194304 + threadIdx.x] = 0.f;
}

// C = WX * W (complex, 256x256). Store bf16 channels: [C0, C1, -C1]
__global__ void prep_C(const float* __restrict__ W, const float* __restrict__ WX,
                       short* __restrict__ Cb) {
  __shared__ float wx0[128], wx1[128];
  const int i = blockIdx.x, j = threadIdx.x;
  if (j < 128) { wx0[j] = WX[i * 128 + j]; wx1[j] = WX[32768 + i * 128 + j]; }
  __syncthreads();
  float c0 = 0.f, c1 = 0.f;
  for (int n = 0; n < 128; n++) {
    const float w0 = W[n * 256 + j], w1 = W[32768 + n * 256 + j];
    c0 += wx0[n] * w0 - wx1[n] * w1;
    c1 += wx0[n] * w1 + wx1[n] * w0;
  }
  Cb[i * 256 + j] = f2bf(c0);
  Cb[65536 + i * 256 + j] = f2bf(c1);
  Cb[131072 + i * 256 + j] = f2bf(-c1);
}

// WXb: bf16 copies [WX0, WX1], layout [ch][k=256][n=128]
__global__ void prep_WX(const float* __restrict__ WX, short* __restrict__ WXb) {
  const int t = blockIdx.x * 256 + threadIdx.x;   // 32768 threads
  WXb[t] = f2bf(WX[t]);
  WXb[32768 + t] = f2bf(WX[32768 + t]);
}

// E0b: [E0_re, -E0_im], layout [ch][m=1024][k=256]
__global__ void prep_E0(const float* __restrict__ E0, short* __restrict__ E0b) {
  const int t = blockIdx.x * 256 + threadIdx.x;   // 524288 threads
  const float v = E0[t];
  E0b[t] = f2bf(t >= 262144 ? -v : v);
}

// E0Tb: [E0_re^T, -E0_im^T], layout [ch][k=256][m=1024]
__global__ void prep_E0T(const float* __restrict__ E0, short* __restrict__ E0Tb) {
  __shared__ float tile[32][33];
  const int mb = blockIdx.x, kb = blockIdx.y, ch = blockIdx.z;
  const int tx = threadIdx.x & 31, ty = threadIdx.x >> 5;   // ty in [0,8)
  #pragma unroll
  for (int r = 0; r < 32; r += 8) {
    tile[ty + r][tx] = E0[ch * 262144 + (mb * 32 + ty + r) * 256 + kb * 32 + tx];
  }
  __syncthreads();
  const float sgn = ch ? -1.f : 1.f;
  #pragma unroll
  for (int r = 0; r < 32; r += 8) {
    E0Tb[ch * 262144 + (kb * 32 + ty + r) * 1024 + mb * 32 + tx] = f2bf(sgn * tile[tx][ty + r]);
  }
}

// ---------------- main fused kernel ----------------
// grid 256 (batch tile of 32), block 1024 (16 waves; wave w: row-tile rt=w&7,
// output channel chw=w>>3).
// LDS: buf0 (32KB) = x bf16 [ch][b=32][256] / aliased z chunk [b=32][512]
//      buf1 (32KB) = gx bf16 [ch][b=32][256] / setup: y [3][b=32][128]
// All LDS rows XOR-swizzled at 16B granules by (row&7).

__global__ __launch_bounds__(1024, 4) void ista_main(
    const float* __restrict__ y,
    const float* __restrict__ etas,
    const float* __restrict__ gammas,
    const short* __restrict__ Cb,
    const short* __restrict__ WXb,
    const short* __restrict__ E0b,
    const short* __restrict__ E0Tb,
    float* __restrict__ out) {
  __shared__ short buf0[16384];
  __shared__ short buf1[16384];

  const int tid = threadIdx.x;
  const int w = tid >> 6;          // wave 0..15
  const int rt = w & 7;            // row-tile
  const int chw = w >> 3;          // owned output channel
  const int lane = tid & 63;
  const int l31 = lane & 31;
  const int h = lane >> 5;         // half-wave
  const int sw = l31 & 7;          // swizzle key
  const int b0 = blockIdx.x * 32;

  // ---- stage y -> buf1: [0]=y_re, [1]=y_im, [2]=-y_im (bf16, swizzled rows of 128)
  {
    const int bt = tid >> 5, j = tid & 31;      // 32 threads per batch row
    const float* yb = y + (size_t)(b0 + bt) * 256;
    const int bsw = (bt & 7);
    const int ch = j >> 4, n8 = (j & 15) << 3;
    const float4 v0 = *(const float4*)(yb + ch * 128 + n8);
    const float4 v1 = *(const float4*)(yb + ch * 128 + n8 + 4);
    s8v pk;
    pk[0] = f2bf(v0.x); pk[1] = f2bf(v0.y); pk[2] = f2bf(v0.z); pk[3] = f2bf(v0.w);
    pk[4] = f2bf(v1.x); pk[5] = f2bf(v1.y); pk[6] = f2bf(v1.z); pk[7] = f2bf(v1.w);
    const int off = bt * 128 + (((n8 >> 3) ^ bsw) << 3);
    *(s8v*)(buf1 + ch * 4096 + off) = pk;
    if (ch == 1) {
      s8v nk;
      #pragma unroll
      for (int e = 0; e < 8; e++) nk[e] = pk[e] ^ (short)0x8000;
      *(s8v*)(buf1 + 8192 + off) = nk;
    }
  }
  // ---- zero buf0 (x = 0): 1024 threads x 16 shorts
  {
    s8v z = {0, 0, 0, 0, 0, 0, 0, 0};
    *(s8v*)(buf0 + tid * 16) = z;
    *(s8v*)(buf0 + tid * 16 + 8) = z;
  }
  __syncthreads();

  // Wave-uniform B-section offsets for the complex-channel split:
  //  ch0 output: A(ch0-weights)*B(x0) + A(neg-ch1-weights)*B(x1)
  //  ch1 output: A(ch0-weights)*B(x1) + A(ch1-weights)*B(x0)
  const int xsec1 = chw ? 8192 : 0;      // first x/gx B-operand section (shorts)
  const int xsec2 = chw ? 0 : 8192;      // second
  const int ysec1 = chw ? 4096 : 0;      // y sections: [y0, y1, -y1] at 0/4096/8192
  const int ysec2 = chw ? 0 : 8192;

  // ---- d~ = WX * y^T (one channel per wave); keep ndt = -d~
  f16v ndt;
  {
    f16v ac;
    #pragma unroll
    for (int r = 0; r < 16; r++) ac[r] = 0.f;
    const int row = rt * 32 + l31;
    #pragma unroll
    for (int kc = 0; kc < 8; kc++) {
      const s8v a0 = *(const s8v*)(WXb + row * 128 + kc * 16 + h * 8);
      const s8v a1 = *(const s8v*)(WXb + 32768 + row * 128 + kc * 16 + h * 8);
      const int yo = l31 * 128 + ((((kc * 2 + h)) ^ sw) << 3);
      const s8v b1 = *(const s8v*)(buf1 + ysec1 + yo);
      const s8v b2 = *(const s8v*)(buf1 + ysec2 + yo);
      ac = MFMA(a0, b1, ac);
      ac = MFMA(a1, b2, ac);
    }
    #pragma unroll
    for (int r = 0; r < 16; r++) ndt[r] = -ac[r];
  }
  __syncthreads();   // buf1 (y) dead; becomes gx buffer

  f16v xr;           // fp32 x state for (rt, chw), C-layout
  #pragma unroll
  for (int r = 0; r < 16; r++) xr[r] = 0.f;
  float ls = 0.f, leq = 0.f, cntf = 0.f;

  // Wave-uniform A-channel offsets for phase A (Cb: [C0, C1, -C1]):
  const int csec2 = chw ? 65536 : 131072;   // second A operand: ch1 -> C1, ch0 -> -C1

  #pragma unroll 1
  for (int it = 1; it <= 10; it++) {
    const float gam = gammas[it];
    const float eta = etas[it];

    // ---- Phase A: acc = C*x - d~ ; gx = x - gam*acc   (one channel per wave)
    f16v ac = ndt;
    {
      const int row = rt * 32 + l31;
      #pragma unroll
      for (int kc = 0; kc < 16; kc++) {
        const s8v a0 = *(const s8v*)(Cb + row * 256 + kc * 16 + h * 8);
        const s8v a1 = *(const s8v*)(Cb + csec2 + row * 256 + kc * 16 + h * 8);
        const int xo = l31 * 256 + ((((kc * 2 + h)) ^ sw) << 3);
        const s8v b1 = *(const s8v*)(buf0 + xsec1 + xo);
        const s8v b2 = *(const s8v*)(buf0 + xsec2 + xo);
        ac = MFMA(a0, b1, ac);
        ac = MFMA(a1, b2, ac);
      }
    }
    f16v gx;
    #pragma unroll
    for (int r = 0; r < 16; r++) gx[r] = xr[r] - gam * ac[r];
    // write gx (bf16) -> buf1 (own channel section)
    #pragma unroll
    for (int r1 = 0; r1 < 4; r1++) {
      const int k0 = rt * 32 + 8 * r1 + 4 * h;
      const int idx = l31 * 256 + (((k0 >> 3) ^ sw) << 3) + (k0 & 7);
      s4v p;
      #pragma unroll
      for (int r0 = 0; r0 < 4; r0++) p[r0] = f2bf(gx[r1 * 4 + r0]);
      *(s4v*)(buf1 + chw * 8192 + idx) = p;
    }
    __syncthreads();

    f16v xm;
    #pragma unroll
    for (int r = 0; r < 16; r++) xm[r] = 0.f;

    #pragma unroll 1
    for (int c = 0; c < 2; c++) {
      // ---- Phase B: z = Re(E0 * gx) for this chunk's 512 m; 1 m-tile per wave
      f16v z;
      #pragma unroll
      for (int r = 0; r < 16; r++) z[r] = 0.f;
      {
        const int m1 = (c * 16 + w) * 32 + l31;
        #pragma unroll
        for (int kc = 0; kc < 16; kc++) {
          const int ka = kc * 16 + h * 8;
          const s8v aE0 = *(const s8v*)(E0b + m1 * 256 + ka);
          const s8v aE1 = *(const s8v*)(E0b + 262144 + m1 * 256 + ka);
          const int xo = l31 * 256 + ((((kc * 2 + h)) ^ sw) << 3);
          const s8v bg0 = *(const s8v*)(buf1 + xo);
          const s8v bg1 = *(const s8v*)(buf1 + 8192 + xo);
          z = MFMA(aE0, bg0, z);
          z = MFMA(aE1, bg1, z);
        }
      }
      // shrink + losses + write z chunk -> buf0 [b=32][512]
      #pragma unroll
      for (int r1 = 0; r1 < 4; r1++) {
        s4v ps;
        #pragma unroll
        for (int r0 = 0; r0 < 4; r0++) {
          const float v = z[r1 * 4 + r0];
          const float av = fabsf(v) - eta;
          float s = 0.f;
          if (av > 0.f) {
            s = (v > 0.f) ? av : -av;
            ls += av;
            if (it == 10 && av > 1e-3f) cntf += 1.f;
          }
          ps[r0] = f2bf(s);
        }
        const int ml = w * 32 + 8 * r1 + 4 * h;
        *(s4v*)(buf0 + l31 * 512 + (((ml >> 3) ^ sw) << 3) + (ml & 7)) = ps;
      }
      __syncthreads();

      // ---- Phase C: xm += E0T(chw) * s  (reduce over this chunk's 512 m)
      {
        const int row = rt * 32 + l31;
        const short* eT = E0Tb + chw * 262144 + row * 1024;
        #pragma unroll
        for (int kc = 0; kc < 32; kc++) {
          const int mcol = c * 512 + kc * 16 + h * 8;
          const s8v aT = *(const s8v*)(eT + mcol);
          const int zo = l31 * 512 + ((((kc * 2 + h)) ^ sw) << 3);
          const s8v bz = *(const s8v*)(buf0 + zo);
          xm = MFMA(aT, bz, xm);
        }
      }
      __syncthreads();
    }

    // ---- Phase D: huber(gx, xm); x = xm; write x (bf16) -> buf0 (own section)
    #pragma unroll
    for (int r = 0; r < 16; r++) {
      const float d = gx[r] - xm[r];
      const float a = fabsf(d);
      leq += (a < 1.f) ? 0.5f * d * d : (a - 0.5f);
      xr[r] = xm[r];
    }
    #pragma unroll
    for (int r1 = 0; r1 < 4; r1++) {
      const int k0 = rt * 32 + 8 * r1 + 4 * h;
      const int idx = l31 * 256 + (((k0 >> 3) ^ sw) << 3) + (k0 & 7);
      s4v p;
      #pragma unroll
      for (int r0 = 0; r0 < 4; r0++) p[r0] = f2bf(xr[r1 * 4 + r0]);
      *(s4v*)(buf0 + chw * 8192 + idx) = p;
    }
    __syncthreads();
  }

  // ---- write x_T (2, 8192, 256) fp32 (own channel, own row-tile)
  {
    const size_t ob = (size_t)chw * 2097152 + (size_t)(b0 + l31) * 256;
    #pragma unroll
    for (int r1 = 0; r1 < 4; r1++) {
      const int k0 = rt * 32 + 8 * r1 + 4 * h;
      float4 v;
      v.x = xr[r1 * 4 + 0]; v.y = xr[r1 * 4 + 1]; v.z = xr[r1 * 4 + 2]; v.w = xr[r1 * 4 + 3];
      *(float4*)(out + ob + k0) = v;
    }
  }
  // ---- scalar reductions
  #pragma unroll
  for (int off = 32; off > 0; off >>= 1) {
    ls += __shfl_down(ls, off);
    leq += __shfl_down(leq, off);
    cntf += __shfl_down(cntf, off);
  }
  if (lane == 0) {
    atomicAdd(out + 4194304, ls * (1.f / 8192.f));
    atomicAdd(out + 4194305, leq * (1.f / (2.f * 256.f * 8192.f * 10.f)));
    atomicAdd(out + 4194306, cntf * (1.f / 8192.f));
  }
}

extern "C" void kernel_launch(void* const* d_in, const int* in_sizes, int n_in,
                              void* d_out, int out_size, void* d_ws, size_t ws_size,
                              hipStream_t stream) {
  (void)in_sizes; (void)n_in; (void)out_size; (void)ws_size;
  const float* y = (const float*)d_in[0];
  const float* W = (const float*)d_in[1];
  const float* WX = (const float*)d_in[2];
  const float* E0 = (const float*)d_in[3];
  const float* etas = (const float*)d_in[4];
  const float* gammas = (const float*)d_in[5];
  float* out = (float*)d_out;

  short* Cb = (short*)d_ws;            // 3 * 65536
  short* WXb = Cb + 196608;            // 2 * 32768
  short* E0b = WXb + 65536;            // 2 * 262144
  short* E0Tb = E0b + 524288;          // 2 * 262144  (total ~2.6 MB)

  zero_tail<<<1, 64, 0, stream>>>(out);
  prep_C<<<256, 256, 0, stream>>>(W, WX, Cb);
  prep_WX<<<128, 256, 0, stream>>>(WX, WXb);
  prep_E0<<<2048, 256, 0, stream>>>(E0, E0b);
  prep_E0T<<<dim3(32, 8, 2), 256, 0, stream>>>(E0, E0Tb);
  ista_main<<<256, 1024, 0, stream>>>(y, etas, gammas, Cb, WXb, E0b, E0Tb, out);
}

// Round 3
// 1218.594 us; speedup vs baseline: 1.0333x; 1.0333x over previous
//
#include <hip/hip_runtime.h>
#include <stdint.h>

// ISTA_Net fused MFMA implementation for gfx950.  Round 3: spill elimination.
// - __launch_bounds__(1024, 1) -> 128-VGPR cap (second arg is min WG/CU; R2's
//   (1024,4) clamped to 64 VGPRs and caused ~1.3GB of scratch HBM traffic).
// - No ndt registers: y kept in LDS, -d~ recomputed in Phase A via (-WX)*y.
// - No fp32 x registers: x state is bf16 in LDS; gx re-read from LDS at huber.
// Shapes: M=1024, N=128, K=256, T=10, BATCH=8192. LAMBD=1.
// Outputs: x_T(2,8192,256) ++ loss_sparse ++ loss_eq/T ++ out_sparse

typedef short s8v __attribute__((ext_vector_type(8)));   // 8 bf16 (4 VGPRs) MFMA operand
typedef short s4v __attribute__((ext_vector_type(4)));
typedef float f16v __attribute__((ext_vector_type(16))); // 32x32 MFMA accumulator

#define MFMA(a, b, c) __builtin_amdgcn_mfma_f32_32x32x16_bf16((a), (b), (c), 0, 0, 0)

__device__ __forceinline__ short f2bf(float f) {
  uint32_t u = __builtin_bit_cast(uint32_t, f);
  u = (u + 0x7FFFu + ((u >> 16) & 1u)) >> 16;   // RNE
  return (short)u;
}
__device__ __forceinline__ float bf2f(short s) {
  uint32_t u = ((uint32_t)(uint16_t)s) << 16;
  return __builtin_bit_cast(float, u);
}

// ---------------- prep kernels ----------------

__global__ void zero_tail(float* out) {
  if (threadIdx.x < 3) out[4194304 + threadIdx.x] = 0.f;
}

// C = WX * W (complex, 256x256). Store bf16 channels: [C0, C1, -C1]
__global__ void prep_C(const float* __restrict__ W, const float* __restrict__ WX,
                       short* __restrict__ Cb) {
  __shared__ float wx0[128], wx1[128];
  const int i = blockIdx.x, j = threadIdx.x;
  if (j < 128) { wx0[j] = WX[i * 128 + j]; wx1[j] = WX[32768 + i * 128 + j]; }
  __syncthreads();
  float c0 = 0.f, c1 = 0.f;
  for (int n = 0; n < 128; n++) {
    const float w0 = W[n * 256 + j], w1 = W[32768 + n * 256 + j];
    c0 += wx0[n] * w0 - wx1[n] * w1;
    c1 += wx0[n] * w1 + wx1[n] * w0;
  }
  Cb[i * 256 + j] = f2bf(c0);
  Cb[65536 + i * 256 + j] = f2bf(c1);
  Cb[131072 + i * 256 + j] = f2bf(-c1);
}

// WXb: NEGATED bf16 copies [-WX0, -WX1], layout [ch][k=256][n=128]
__global__ void prep_WX(const float* __restrict__ WX, short* __restrict__ WXb) {
  const int t = blockIdx.x * 256 + threadIdx.x;   // 32768 threads
  WXb[t] = f2bf(-WX[t]);
  WXb[32768 + t] = f2bf(-WX[32768 + t]);
}

// E0b: [E0_re, -E0_im], layout [ch][m=1024][k=256]
__global__ void prep_E0(const float* __restrict__ E0, short* __restrict__ E0b) {
  const int t = blockIdx.x * 256 + threadIdx.x;   // 524288 threads
  const float v = E0[t];
  E0b[t] = f2bf(t >= 262144 ? -v : v);
}

// E0Tb: [E0_re^T, -E0_im^T], layout [ch][k=256][m=1024]
__global__ void prep_E0T(const float* __restrict__ E0, short* __restrict__ E0Tb) {
  __shared__ float tile[32][33];
  const int mb = blockIdx.x, kb = blockIdx.y, ch = blockIdx.z;
  const int tx = threadIdx.x & 31, ty = threadIdx.x >> 5;   // ty in [0,8)
  #pragma unroll
  for (int r = 0; r < 32; r += 8) {
    tile[ty + r][tx] = E0[ch * 262144 + (mb * 32 + ty + r) * 256 + kb * 32 + tx];
  }
  __syncthreads();
  const float sgn = ch ? -1.f : 1.f;
  #pragma unroll
  for (int r = 0; r < 32; r += 8) {
    E0Tb[ch * 262144 + (kb * 32 + ty + r) * 1024 + mb * 32 + tx] = f2bf(sgn * tile[tx][ty + r]);
  }
}

// ---------------- main fused kernel ----------------
// grid 256 (batch tile of 32), block 1024 (16 waves; wave w: row-tile rt=w&7,
// output channel chw=w>>3).
// LDS: buf0 (32KB) = x bf16 [ch][b=32][256] / aliased z chunk [b=32][512]
//      buf1 (32KB) = gx bf16 [ch][b=32][256]
//      bufy (24KB) = y bf16 [y0|y1|-y1][b=32][128]  (persistent)
// All LDS rows XOR-swizzled at 16B granules by (row&7).

__global__ __launch_bounds__(1024, 1) void ista_main(
    const float* __restrict__ y,
    const float* __restrict__ etas,
    const float* __restrict__ gammas,
    const short* __restrict__ Cb,
    const short* __restrict__ WXb,
    const short* __restrict__ E0b,
    const short* __restrict__ E0Tb,
    float* __restrict__ out) {
  __shared__ short buf0[16384];
  __shared__ short buf1[16384];
  __shared__ short bufy[12288];

  const int tid = threadIdx.x;
  const int w = tid >> 6;          // wave 0..15
  const int rt = w & 7;            // row-tile
  const int chw = w >> 3;          // owned output channel
  const int lane = tid & 63;
  const int l31 = lane & 31;
  const int h = lane >> 5;         // half-wave
  const int sw = l31 & 7;          // swizzle key
  const int b0 = blockIdx.x * 32;

  // ---- stage y -> bufy: [0]=y_re, [1]=y_im, [2]=-y_im (bf16, swizzled rows of 128)
  {
    const int bt = tid >> 5, j = tid & 31;      // 32 threads per batch row
    const float* yb = y + (size_t)(b0 + bt) * 256;
    const int bsw = (bt & 7);
    const int ch = j >> 4, n8 = (j & 15) << 3;
    const float4 v0 = *(const float4*)(yb + ch * 128 + n8);
    const float4 v1 = *(const float4*)(yb + ch * 128 + n8 + 4);
    s8v pk;
    pk[0] = f2bf(v0.x); pk[1] = f2bf(v0.y); pk[2] = f2bf(v0.z); pk[3] = f2bf(v0.w);
    pk[4] = f2bf(v1.x); pk[5] = f2bf(v1.y); pk[6] = f2bf(v1.z); pk[7] = f2bf(v1.w);
    const int off = bt * 128 + (((n8 >> 3) ^ bsw) << 3);
    *(s8v*)(bufy + ch * 4096 + off) = pk;
    if (ch == 1) {
      s8v nk;
      #pragma unroll
      for (int e = 0; e < 8; e++) nk[e] = pk[e] ^ (short)0x8000;
      *(s8v*)(bufy + 8192 + off) = nk;
    }
  }
  // ---- zero buf0 (x = 0): 1024 threads x 16 shorts
  {
    s8v z = {0, 0, 0, 0, 0, 0, 0, 0};
    *(s8v*)(buf0 + tid * 16) = z;
    *(s8v*)(buf0 + tid * 16 + 8) = z;
  }
  __syncthreads();

  // Wave-uniform section offsets for the complex-channel split.
  //  d~ recompute with negated WX weights [nWX0, nWX1]:
  //   ch0: -d0 = nWX0*y0 + nWX1*(-y1);  ch1: -d1 = nWX0*y1 + nWX1*y0
  const int ysec1 = chw ? 4096 : 0;      // y sections: [y0, y1, -y1] at 0/4096/8192
  const int ysec2 = chw ? 0 : 8192;
  //  C*x (Cb sections [C0, C1, -C1]):
  //   ch0: C0*x0 + (-C1)*x1;  ch1: C0*x1 + C1*x0
  const int xsec1 = chw ? 8192 : 0;      // first x B-operand section (shorts)
  const int xsec2 = chw ? 0 : 8192;      // second
  const int csec2 = chw ? 65536 : 131072;

  float ls = 0.f, leq = 0.f, cntf = 0.f;
  f16v xm;
  #pragma unroll
  for (int r = 0; r < 16; r++) xm[r] = 0.f;

  #pragma unroll 1
  for (int it = 1; it <= 10; it++) {
    const float gam = gammas[it];
    const float eta = etas[it];
    const int row = rt * 32 + l31;

    // ---- Phase A: ac = C*x - d~ ; gx = x - gam*ac  (one channel per wave)
    f16v ac;
    #pragma unroll
    for (int r = 0; r < 16; r++) ac[r] = 0.f;
    #pragma unroll
    for (int kc = 0; kc < 8; kc++) {       // -d~ = (-WX) * y
      const s8v a0 = *(const s8v*)(WXb + row * 128 + kc * 16 + h * 8);
      const s8v a1 = *(const s8v*)(WXb + 32768 + row * 128 + kc * 16 + h * 8);
      const int yo = l31 * 128 + ((((kc * 2 + h)) ^ sw) << 3);
      const s8v b1 = *(const s8v*)(bufy + ysec1 + yo);
      const s8v b2 = *(const s8v*)(bufy + ysec2 + yo);
      ac = MFMA(a0, b1, ac);
      ac = MFMA(a1, b2, ac);
    }
    #pragma unroll
    for (int kc = 0; kc < 16; kc++) {      // + C * x
      const s8v a0 = *(const s8v*)(Cb + row * 256 + kc * 16 + h * 8);
      const s8v a1 = *(const s8v*)(Cb + csec2 + row * 256 + kc * 16 + h * 8);
      const int xo = l31 * 256 + ((((kc * 2 + h)) ^ sw) << 3);
      const s8v b1 = *(const s8v*)(buf0 + xsec1 + xo);
      const s8v b2 = *(const s8v*)(buf0 + xsec2 + xo);
      ac = MFMA(a0, b1, ac);
      ac = MFMA(a1, b2, ac);
    }
    // gx = x - gam*ac  (x read per-lane from LDS bf16); write gx bf16 -> buf1
    #pragma unroll
    for (int r1 = 0; r1 < 4; r1++) {
      const int k0 = rt * 32 + 8 * r1 + 4 * h;
      const int idx = l31 * 256 + (((k0 >> 3) ^ sw) << 3) + (k0 & 7);
      const s4v xv = *(const s4v*)(buf0 + chw * 8192 + idx);
      s4v p;
      #pragma unroll
      for (int r0 = 0; r0 < 4; r0++) {
        p[r0] = f2bf(bf2f(xv[r0]) - gam * ac[r1 * 4 + r0]);
      }
      *(s4v*)(buf1 + chw * 8192 + idx) = p;
    }
    __syncthreads();

    #pragma unroll
    for (int r = 0; r < 16; r++) xm[r] = 0.f;

    #pragma unroll 1
    for (int c = 0; c < 2; c++) {
      // ---- Phase B: z = Re(E0 * gx) for this chunk's 512 m; 1 m-tile per wave
      f16v z;
      #pragma unroll
      for (int r = 0; r < 16; r++) z[r] = 0.f;
      {
        const int m1 = (c * 16 + w) * 32 + l31;
        #pragma unroll
        for (int kc = 0; kc < 16; kc++) {
          const int ka = kc * 16 + h * 8;
          const s8v aE0 = *(const s8v*)(E0b + m1 * 256 + ka);
          const s8v aE1 = *(const s8v*)(E0b + 262144 + m1 * 256 + ka);
          const int xo = l31 * 256 + ((((kc * 2 + h)) ^ sw) << 3);
          const s8v bg0 = *(const s8v*)(buf1 + xo);
          const s8v bg1 = *(const s8v*)(buf1 + 8192 + xo);
          z = MFMA(aE0, bg0, z);
          z = MFMA(aE1, bg1, z);
        }
      }
      // shrink + losses + write z chunk -> buf0 [b=32][512]
      #pragma unroll
      for (int r1 = 0; r1 < 4; r1++) {
        s4v ps;
        #pragma unroll
        for (int r0 = 0; r0 < 4; r0++) {
          const float v = z[r1 * 4 + r0];
          const float av = fabsf(v) - eta;
          float s = 0.f;
          if (av > 0.f) {
            s = (v > 0.f) ? av : -av;
            ls += av;
            if (it == 10 && av > 1e-3f) cntf += 1.f;
          }
          ps[r0] = f2bf(s);
        }
        const int ml = w * 32 + 8 * r1 + 4 * h;
        *(s4v*)(buf0 + l31 * 512 + (((ml >> 3) ^ sw) << 3) + (ml & 7)) = ps;
      }
      __syncthreads();

      // ---- Phase C: xm += E0T(chw) * s  (reduce over this chunk's 512 m)
      {
        const short* eT = E0Tb + chw * 262144 + row * 1024;
        #pragma unroll
        for (int kc = 0; kc < 32; kc++) {
          const int mcol = c * 512 + kc * 16 + h * 8;
          const s8v aT = *(const s8v*)(eT + mcol);
          const int zo = l31 * 512 + ((((kc * 2 + h)) ^ sw) << 3);
          const s8v bz = *(const s8v*)(buf0 + zo);
          xm = MFMA(aT, bz, xm);
        }
      }
      __syncthreads();
    }

    // ---- Phase D: huber(gx, xm); x = xm (bf16) -> buf0 (own section)
    #pragma unroll
    for (int r1 = 0; r1 < 4; r1++) {
      const int k0 = rt * 32 + 8 * r1 + 4 * h;
      const int idx = l31 * 256 + (((k0 >> 3) ^ sw) << 3) + (k0 & 7);
      const s4v gv = *(const s4v*)(buf1 + chw * 8192 + idx);
      s4v p;
      #pragma unroll
      for (int r0 = 0; r0 < 4; r0++) {
        const float xv = xm[r1 * 4 + r0];
        const float d = bf2f(gv[r0]) - xv;
        const float a = fabsf(d);
        leq += (a < 1.f) ? 0.5f * d * d : (a - 0.5f);
        p[r0] = f2bf(xv);
      }
      *(s4v*)(buf0 + chw * 8192 + idx) = p;
    }
    __syncthreads();
  }

  // ---- write x_T (2, 8192, 256) fp32 from final xm (own channel, own row-tile)
  {
    const size_t ob = (size_t)chw * 2097152 + (size_t)(b0 + l31) * 256;
    #pragma unroll
    for (int r1 = 0; r1 < 4; r1++) {
      const int k0 = rt * 32 + 8 * r1 + 4 * h;
      float4 v;
      v.x = xm[r1 * 4 + 0]; v.y = xm[r1 * 4 + 1]; v.z = xm[r1 * 4 + 2]; v.w = xm[r1 * 4 + 3];
      *(float4*)(out + ob + k0) = v;
    }
  }
  // ---- scalar reductions
  #pragma unroll
  for (int off = 32; off > 0; off >>= 1) {
    ls += __shfl_down(ls, off);
    leq += __shfl_down(leq, off);
    cntf += __shfl_down(cntf, off);
  }
  if (lane == 0) {
    atomicAdd(out + 4194304, ls * (1.f / 8192.f));
    atomicAdd(out + 4194305, leq * (1.f / (2.f * 256.f * 8192.f * 10.f)));
    atomicAdd(out + 4194306, cntf * (1.f / 8192.f));
  }
}

extern "C" void kernel_launch(void* const* d_in, const int* in_sizes, int n_in,
                              void* d_out, int out_size, void* d_ws, size_t ws_size,
                              hipStream_t stream) {
  (void)in_sizes; (void)n_in; (void)out_size; (void)ws_size;
  const float* y = (const float*)d_in[0];
  const float* W = (const float*)d_in[1];
  const float* WX = (const float*)d_in[2];
  const float* E0 = (const float*)d_in[3];
  const float* etas = (const float*)d_in[4];
  const float* gammas = (const float*)d_in[5];
  float* out = (float*)d_out;

  short* Cb = (short*)d_ws;            // 3 * 65536
  short* WXb = Cb + 196608;            // 2 * 32768
  short* E0b = WXb + 65536;            // 2 * 262144
  short* E0Tb = E0b + 524288;          // 2 * 262144  (total ~2.6 MB)

  zero_tail<<<1, 64, 0, stream>>>(out);
  prep_C<<<256, 256, 0, stream>>>(W, WX, Cb);
  prep_WX<<<128, 256, 0, stream>>>(WX, WXb);
  prep_E0<<<2048, 256, 0, stream>>>(E0, E0b);
  prep_E0T<<<dim3(32, 8, 2), 256, 0, stream>>>(E0, E0Tb);
  ista_main<<<256, 1024, 0, stream>>>(y, etas, gammas, Cb, WXb, E0b, E0Tb, out);
}

// Round 4
// 1003.590 us; speedup vs baseline: 1.2547x; 1.2142x over previous
//
#include <hip/hip_runtime.h>
#include <stdint.h>

// ISTA_Net fused MFMA implementation for gfx950.  Round 4:
// - amdgpu_waves_per_eu(4,4): pin occupancy to 4 waves/EU so the allocator
//   gets the full 128-reg unified budget (R2/R3 heuristically chose 8/EU ->
//   64 arch VGPRs -> ~240MB scratch spill traffic per launch).
// - Fragment-major weight packing: all MFMA A-fragments stored contiguously
//   ([tile][kc][h][lane][8]) so each wave A-load is one coalesced 1KB burst
//   (8 cache lines) instead of 64 scattered 16B requests (64 lines).
// Shapes: M=1024, N=128, K=256, T=10, BATCH=8192. LAMBD=1.
// Outputs: x_T(2,8192,256) ++ loss_sparse ++ loss_eq/T ++ out_sparse

typedef short s8v __attribute__((ext_vector_type(8)));   // 8 bf16 (4 VGPRs) MFMA operand
typedef short s4v __attribute__((ext_vector_type(4)));
typedef float f16v __attribute__((ext_vector_type(16))); // 32x32 MFMA accumulator

#define MFMA(a, b, c) __builtin_amdgcn_mfma_f32_32x32x16_bf16((a), (b), (c), 0, 0, 0)

__device__ __forceinline__ short f2bf(float f) {
  uint32_t u = __builtin_bit_cast(uint32_t, f);
  u = (u + 0x7FFFu + ((u >> 16) & 1u)) >> 16;   // RNE
  return (short)u;
}
__device__ __forceinline__ float bf2f(short s) {
  uint32_t u = ((uint32_t)(uint16_t)s) << 16;
  return __builtin_bit_cast(float, u);
}

// ---------------- prep kernels (all outputs fragment-major packed) ----------------
// Packed layout per section: idx = ((tile*KC + kc)*2 + h)*256 + l31*8 + j
//   A-fragment element (l31, h, j) = Src[tile*32 + l31][kc*16 + h*8 + j]

__global__ void zero_tail(float* out) {
  if (threadIdx.x < 3) out[4194304 + threadIdx.x] = 0.f;
}

// WXbp: sections [-WX0, -WX1] (32768 shorts each). A-row = k(256), A-col = n(128), KC=8.
__global__ void prep_pack_WX(const float* __restrict__ WX, short* __restrict__ WXbp) {
  const int idx = blockIdx.x * 256 + threadIdx.x;   // 65536 threads
  const int sec = idx >> 15, r = idx & 32767;
  const int j = r & 7, l31 = (r >> 3) & 31, h = (r >> 8) & 1, kc = (r >> 9) & 7, rt = r >> 12;
  const int row = rt * 32 + l31, col = kc * 16 + h * 8 + j;
  WXbp[idx] = f2bf(-WX[sec * 32768 + row * 128 + col]);
}

// Cbp: sections [C0, C1, -C1] (65536 shorts each), C = WX*W complex (256x256), KC=16.
__global__ void prep_pack_C(const float* __restrict__ W, const float* __restrict__ WX,
                            short* __restrict__ Cbp) {
  const int idx = blockIdx.x * 256 + threadIdx.x;   // 196608 threads
  const int sec = idx >> 16, r = idx & 65535;
  const int j = r & 7, l31 = (r >> 3) & 31, h = (r >> 8) & 1, kc = (r >> 9) & 15, rt = r >> 13;
  const int i = rt * 32 + l31, col = kc * 16 + h * 8 + j;   // C[i][col]
  float c0 = 0.f, c1 = 0.f;
  for (int n = 0; n < 128; n++) {
    const float wx0 = WX[i * 128 + n], wx1 = WX[32768 + i * 128 + n];
    const float w0 = W[n * 256 + col], w1 = W[32768 + n * 256 + col];
    c0 += wx0 * w0 - wx1 * w1;
    c1 += wx0 * w1 + wx1 * w0;
  }
  Cbp[idx] = f2bf(sec == 0 ? c0 : (sec == 1 ? c1 : -c1));
}

// E0bp: sections [E0_re, -E0_im] (262144 shorts each). A-row = m(1024), A-col = k(256), KC=16.
__global__ void prep_pack_E0(const float* __restrict__ E0, short* __restrict__ E0bp) {
  const int idx = blockIdx.x * 256 + threadIdx.x;   // 524288 threads
  const int sec = idx >> 18, r = idx & 262143;
  const int j = r & 7, l31 = (r >> 3) & 31, h = (r >> 8) & 1, kc = (r >> 9) & 15, mt = r >> 13;
  const int m = mt * 32 + l31, k = kc * 16 + h * 8 + j;
  const float v = E0[sec * 262144 + m * 256 + k];
  E0bp[idx] = f2bf(sec ? -v : v);
}

// E0Tbp: sections ch [E0_re^T, -E0_im^T] (262144 shorts each). A-row = k(256), A-col = m(1024), KC=64.
__global__ void prep_pack_E0T(const float* __restrict__ E0, short* __restrict__ E0Tbp) {
  const int idx = blockIdx.x * 256 + threadIdx.x;   // 524288 threads
  const int ch = idx >> 18, r = idx & 262143;
  const int j = r & 7, l31 = (r >> 3) & 31, h = (r >> 8) & 1, kc = (r >> 9) & 63, rt = r >> 15;
  const int krow = rt * 32 + l31, mcol = kc * 16 + h * 8 + j;
  const float v = E0[ch * 262144 + mcol * 256 + krow];
  E0Tbp[idx] = f2bf(ch ? -v : v);
}

// ---------------- main fused kernel ----------------
// grid 256 (batch tile of 32), block 1024 (16 waves; wave w: row-tile rt=w&7,
// output channel chw=w>>3).
// LDS: buf0 (32KB) = x bf16 [ch][b=32][256] / aliased z chunk [b=32][512]
//      buf1 (32KB) = gx bf16 [ch][b=32][256]
//      bufy (12KB) = y bf16 [y0|y1|-y1][b=32][128]  (persistent)
// All LDS rows XOR-swizzled at 16B granules by (row&7).

__global__ __attribute__((amdgpu_flat_work_group_size(1024, 1024), amdgpu_waves_per_eu(4, 4)))
void ista_main(
    const float* __restrict__ y,
    const float* __restrict__ etas,
    const float* __restrict__ gammas,
    const short* __restrict__ Cbp,
    const short* __restrict__ WXbp,
    const short* __restrict__ E0bp,
    const short* __restrict__ E0Tbp,
    float* __restrict__ out) {
  __shared__ short buf0[16384];
  __shared__ short buf1[16384];
  __shared__ short bufy[12288];

  const int tid = threadIdx.x;
  const int w = tid >> 6;          // wave 0..15
  const int rt = w & 7;            // row-tile
  const int chw = w >> 3;          // owned output channel
  const int lane = tid & 63;
  const int l31 = lane & 31;
  const int h = lane >> 5;         // half-wave
  const int sw = l31 & 7;          // swizzle key
  const int b0 = blockIdx.x * 32;
  const int lq = l31 * 8;          // packed-fragment lane offset (shorts)

  // ---- stage y -> bufy: [0]=y_re, [1]=y_im, [2]=-y_im (bf16, swizzled rows of 128)
  {
    const int bt = tid >> 5, j = tid & 31;      // 32 threads per batch row
    const float* yb = y + (size_t)(b0 + bt) * 256;
    const int bsw = (bt & 7);
    const int ch = j >> 4, n8 = (j & 15) << 3;
    const float4 v0 = *(const float4*)(yb + ch * 128 + n8);
    const float4 v1 = *(const float4*)(yb + ch * 128 + n8 + 4);
    s8v pk;
    pk[0] = f2bf(v0.x); pk[1] = f2bf(v0.y); pk[2] = f2bf(v0.z); pk[3] = f2bf(v0.w);
    pk[4] = f2bf(v1.x); pk[5] = f2bf(v1.y); pk[6] = f2bf(v1.z); pk[7] = f2bf(v1.w);
    const int off = bt * 128 + (((n8 >> 3) ^ bsw) << 3);
    *(s8v*)(bufy + ch * 4096 + off) = pk;
    if (ch == 1) {
      s8v nk;
      #pragma unroll
      for (int e = 0; e < 8; e++) nk[e] = pk[e] ^ (short)0x8000;
      *(s8v*)(bufy + 8192 + off) = nk;
    }
  }
  // ---- zero buf0 (x = 0): 1024 threads x 16 shorts
  {
    s8v z = {0, 0, 0, 0, 0, 0, 0, 0};
    *(s8v*)(buf0 + tid * 16) = z;
    *(s8v*)(buf0 + tid * 16 + 8) = z;
  }
  __syncthreads();

  // Wave-uniform section offsets for the complex-channel split.
  //  -d~ with negated WX sections [nWX0, nWX1]:
  //   ch0: nWX0*y0 + nWX1*(-y1);  ch1: nWX0*y1 + nWX1*y0
  const int ysec1 = chw ? 4096 : 0;      // y sections: [y0, y1, -y1] at 0/4096/8192
  const int ysec2 = chw ? 0 : 8192;
  //  C*x (Cbp sections [C0, C1, -C1]):
  //   ch0: C0*x0 + (-C1)*x1;  ch1: C0*x1 + C1*x0
  const int xsec1 = chw ? 8192 : 0;      // first x B-operand LDS section (shorts)
  const int xsec2 = chw ? 0 : 8192;      // second
  const int csec2 = chw ? 65536 : 131072;

  float ls = 0.f, leq = 0.f, cntf = 0.f;
  f16v xm;
  #pragma unroll
  for (int r = 0; r < 16; r++) xm[r] = 0.f;

  #pragma unroll 1
  for (int it = 1; it <= 10; it++) {
    const float gam = gammas[it];
    const float eta = etas[it];

    // ---- Phase A: ac = C*x - d~ ; gx = x - gam*ac  (one channel per wave)
    f16v ac;
    #pragma unroll
    for (int r = 0; r < 16; r++) ac[r] = 0.f;
    #pragma unroll
    for (int kc = 0; kc < 8; kc++) {       // -d~ = (-WX) * y
      const int pa = ((rt * 8 + kc) * 2 + h) * 256 + lq;
      const s8v a0 = *(const s8v*)(WXbp + pa);
      const s8v a1 = *(const s8v*)(WXbp + 32768 + pa);
      const int yo = l31 * 128 + ((((kc * 2 + h)) ^ sw) << 3);
      const s8v b1 = *(const s8v*)(bufy + ysec1 + yo);
      const s8v b2 = *(const s8v*)(bufy + ysec2 + yo);
      ac = MFMA(a0, b1, ac);
      ac = MFMA(a1, b2, ac);
    }
    #pragma unroll
    for (int kc = 0; kc < 16; kc++) {      // + C * x
      const int pa = ((rt * 16 + kc) * 2 + h) * 256 + lq;
      const s8v a0 = *(const s8v*)(Cbp + pa);
      const s8v a1 = *(const s8v*)(Cbp + csec2 + pa);
      const int xo = l31 * 256 + ((((kc * 2 + h)) ^ sw) << 3);
      const s8v b1 = *(const s8v*)(buf0 + xsec1 + xo);
      const s8v b2 = *(const s8v*)(buf0 + xsec2 + xo);
      ac = MFMA(a0, b1, ac);
      ac = MFMA(a1, b2, ac);
    }
    // gx = x - gam*ac  (x read per-lane from LDS bf16); write gx bf16 -> buf1
    #pragma unroll
    for (int r1 = 0; r1 < 4; r1++) {
      const int k0 = rt * 32 + 8 * r1 + 4 * h;
      const int idx = l31 * 256 + (((k0 >> 3) ^ sw) << 3) + (k0 & 7);
      const s4v xv = *(const s4v*)(buf0 + chw * 8192 + idx);
      s4v p;
      #pragma unroll
      for (int r0 = 0; r0 < 4; r0++) {
        p[r0] = f2bf(bf2f(xv[r0]) - gam * ac[r1 * 4 + r0]);
      }
      *(s4v*)(buf1 + chw * 8192 + idx) = p;
    }
    __syncthreads();

    #pragma unroll
    for (int r = 0; r < 16; r++) xm[r] = 0.f;

    #pragma unroll 1
    for (int c = 0; c < 2; c++) {
      // ---- Phase B: z = Re(E0 * gx) for this chunk's 512 m; 1 m-tile per wave
      f16v z;
      #pragma unroll
      for (int r = 0; r < 16; r++) z[r] = 0.f;
      {
        const int mt = c * 16 + w;
        #pragma unroll
        for (int kc = 0; kc < 16; kc++) {
          const int pa = ((mt * 16 + kc) * 2 + h) * 256 + lq;
          const s8v aE0 = *(const s8v*)(E0bp + pa);
          const s8v aE1 = *(const s8v*)(E0bp + 262144 + pa);
          const int xo = l31 * 256 + ((((kc * 2 + h)) ^ sw) << 3);
          const s8v bg0 = *(const s8v*)(buf1 + xo);
          const s8v bg1 = *(const s8v*)(buf1 + 8192 + xo);
          z = MFMA(aE0, bg0, z);
          z = MFMA(aE1, bg1, z);
        }
      }
      // shrink + losses + write z chunk -> buf0 [b=32][512]
      #pragma unroll
      for (int r1 = 0; r1 < 4; r1++) {
        s4v ps;
        #pragma unroll
        for (int r0 = 0; r0 < 4; r0++) {
          const float v = z[r1 * 4 + r0];
          const float av = fabsf(v) - eta;
          float s = 0.f;
          if (av > 0.f) {
            s = (v > 0.f) ? av : -av;
            ls += av;
            if (it == 10 && av > 1e-3f) cntf += 1.f;
          }
          ps[r0] = f2bf(s);
        }
        const int ml = w * 32 + 8 * r1 + 4 * h;
        *(s4v*)(buf0 + l31 * 512 + (((ml >> 3) ^ sw) << 3) + (ml & 7)) = ps;
      }
      __syncthreads();

      // ---- Phase C: xm += E0T(chw) * s  (reduce over this chunk's 512 m)
      {
        const short* eT = E0Tbp + chw * 262144;
        #pragma unroll
        for (int kc = 0; kc < 32; kc++) {
          const int pa = ((rt * 64 + c * 32 + kc) * 2 + h) * 256 + lq;
          const s8v aT = *(const s8v*)(eT + pa);
          const int zo = l31 * 512 + ((((kc * 2 + h)) ^ sw) << 3);
          const s8v bz = *(const s8v*)(buf0 + zo);
          xm = MFMA(aT, bz, xm);
        }
      }
      __syncthreads();
    }

    // ---- Phase D: huber(gx, xm); x = xm (bf16) -> buf0 (own section)
    #pragma unroll
    for (int r1 = 0; r1 < 4; r1++) {
      const int k0 = rt * 32 + 8 * r1 + 4 * h;
      const int idx = l31 * 256 + (((k0 >> 3) ^ sw) << 3) + (k0 & 7);
      const s4v gv = *(const s4v*)(buf1 + chw * 8192 + idx);
      s4v p;
      #pragma unroll
      for (int r0 = 0; r0 < 4; r0++) {
        const float xv = xm[r1 * 4 + r0];
        const float d = bf2f(gv[r0]) - xv;
        const float a = fabsf(d);
        leq += (a < 1.f) ? 0.5f * d * d : (a - 0.5f);
        p[r0] = f2bf(xv);
      }
      *(s4v*)(buf0 + chw * 8192 + idx) = p;
    }
    __syncthreads();
  }

  // ---- write x_T (2, 8192, 256) fp32 from final xm (own channel, own row-tile)
  {
    const size_t ob = (size_t)chw * 2097152 + (size_t)(b0 + l31) * 256;
    #pragma unroll
    for (int r1 = 0; r1 < 4; r1++) {
      const int k0 = rt * 32 + 8 * r1 + 4 * h;
      float4 v;
      v.x = xm[r1 * 4 + 0]; v.y = xm[r1 * 4 + 1]; v.z = xm[r1 * 4 + 2]; v.w = xm[r1 * 4 + 3];
      *(float4*)(out + ob + k0) = v;
    }
  }
  // ---- scalar reductions
  #pragma unroll
  for (int off = 32; off > 0; off >>= 1) {
    ls += __shfl_down(ls, off);
    leq += __shfl_down(leq, off);
    cntf += __shfl_down(cntf, off);
  }
  if (lane == 0) {
    atomicAdd(out + 4194304, ls * (1.f / 8192.f));
    atomicAdd(out + 4194305, leq * (1.f / (2.f * 256.f * 8192.f * 10.f)));
    atomicAdd(out + 4194306, cntf * (1.f / 8192.f));
  }
}

extern "C" void kernel_launch(void* const* d_in, const int* in_sizes, int n_in,
                              void* d_out, int out_size, void* d_ws, size_t ws_size,
                              hipStream_t stream) {
  (void)in_sizes; (void)n_in; (void)out_size; (void)ws_size;
  const float* y = (const float*)d_in[0];
  const float* W = (const float*)d_in[1];
  const float* WX = (const float*)d_in[2];
  const float* E0 = (const float*)d_in[3];
  const float* etas = (const float*)d_in[4];
  const float* gammas = (const float*)d_in[5];
  float* out = (float*)d_out;

  short* Cbp = (short*)d_ws;           // 3 * 65536
  short* WXbp = Cbp + 196608;          // 2 * 32768
  short* E0bp = WXbp + 65536;          // 2 * 262144
  short* E0Tbp = E0bp + 524288;        // 2 * 262144  (total ~2.6 MB)

  zero_tail<<<1, 64, 0, stream>>>(out);
  prep_pack_C<<<768, 256, 0, stream>>>(W, WX, Cbp);
  prep_pack_WX<<<256, 256, 0, stream>>>(WX, WXbp);
  prep_pack_E0<<<2048, 256, 0, stream>>>(E0, E0bp);
  prep_pack_E0T<<<2048, 256, 0, stream>>>(E0, E0Tbp);
  ista_main<<<256, 1024, 0, stream>>>(y, etas, gammas, Cbp, WXbp, E0bp, E0Tbp, out);
}

// Round 5
// 917.766 us; speedup vs baseline: 1.3720x; 1.0935x over previous
//
#include <hip/hip_runtime.h>
#include <stdint.h>

// ISTA_Net fused MFMA implementation for gfx950.  Round 5:
// 8-wave blocks (512 thr) + amdgpu_waves_per_eu(2,2) -> 256 unified regs/wave
// (R2-R4's 16-wave blocks structurally cap at 128/wave -> 64 arch -> ~250MB
// scratch spill in every phase's critical path).  Each wave owns BOTH complex
// channels of its row-tile (Phases A/C: 2 accumulators) and 2 m-tiles (Phase
// B).  Keeps R4's fragment-major packed weights (1KB coalesced A-loads) and
// bf16 LDS x-state (no fp32 state registers).
// Shapes: M=1024, N=128, K=256, T=10, BATCH=8192. LAMBD=1.
// Outputs: x_T(2,8192,256) ++ loss_sparse ++ loss_eq/T ++ out_sparse

typedef short s8v __attribute__((ext_vector_type(8)));   // 8 bf16 (4 VGPRs) MFMA operand
typedef short s4v __attribute__((ext_vector_type(4)));
typedef float f16v __attribute__((ext_vector_type(16))); // 32x32 MFMA accumulator

#define MFMA(a, b, c) __builtin_amdgcn_mfma_f32_32x32x16_bf16((a), (b), (c), 0, 0, 0)

__device__ __forceinline__ short f2bf(float f) {
  uint32_t u = __builtin_bit_cast(uint32_t, f);
  u = (u + 0x7FFFu + ((u >> 16) & 1u)) >> 16;   // RNE
  return (short)u;
}
__device__ __forceinline__ float bf2f(short s) {
  uint32_t u = ((uint32_t)(uint16_t)s) << 16;
  return __builtin_bit_cast(float, u);
}

// ---------------- prep kernels (all outputs fragment-major packed) ----------------
// Packed layout per section: idx = ((tile*KC + kc)*2 + h)*256 + l31*8 + j
//   A-fragment element (l31, h, j) = Src[tile*32 + l31][kc*16 + h*8 + j]

__global__ void zero_tail(float* out) {
  if (threadIdx.x < 3) out[4194304 + threadIdx.x] = 0.f;
}

// WXbp: sections [-WX0, -WX1] (32768 shorts each). A-row = k(256), A-col = n(128), KC=8.
__global__ void prep_pack_WX(const float* __restrict__ WX, short* __restrict__ WXbp) {
  const int idx = blockIdx.x * 256 + threadIdx.x;   // 65536 threads
  const int sec = idx >> 15, r = idx & 32767;
  const int j = r & 7, l31 = (r >> 3) & 31, h = (r >> 8) & 1, kc = (r >> 9) & 7, rt = r >> 12;
  const int row = rt * 32 + l31, col = kc * 16 + h * 8 + j;
  WXbp[idx] = f2bf(-WX[sec * 32768 + row * 128 + col]);
}

// Cbp: sections [C0, C1, -C1] (65536 shorts each), C = WX*W complex (256x256), KC=16.
__global__ void prep_pack_C(const float* __restrict__ W, const float* __restrict__ WX,
                            short* __restrict__ Cbp) {
  const int idx = blockIdx.x * 256 + threadIdx.x;   // 196608 threads
  const int sec = idx >> 16, r = idx & 65535;
  const int j = r & 7, l31 = (r >> 3) & 31, h = (r >> 8) & 1, kc = (r >> 9) & 15, rt = r >> 13;
  const int i = rt * 32 + l31, col = kc * 16 + h * 8 + j;   // C[i][col]
  float c0 = 0.f, c1 = 0.f;
  for (int n = 0; n < 128; n++) {
    const float wx0 = WX[i * 128 + n], wx1 = WX[32768 + i * 128 + n];
    const float w0 = W[n * 256 + col], w1 = W[32768 + n * 256 + col];
    c0 += wx0 * w0 - wx1 * w1;
    c1 += wx0 * w1 + wx1 * w0;
  }
  Cbp[idx] = f2bf(sec == 0 ? c0 : (sec == 1 ? c1 : -c1));
}

// E0bp: sections [E0_re, -E0_im] (262144 shorts each). A-row = m(1024), A-col = k(256), KC=16.
__global__ void prep_pack_E0(const float* __restrict__ E0, short* __restrict__ E0bp) {
  const int idx = blockIdx.x * 256 + threadIdx.x;   // 524288 threads
  const int sec = idx >> 18, r = idx & 262143;
  const int j = r & 7, l31 = (r >> 3) & 31, h = (r >> 8) & 1, kc = (r >> 9) & 15, mt = r >> 13;
  const int m = mt * 32 + l31, k = kc * 16 + h * 8 + j;
  const float v = E0[sec * 262144 + m * 256 + k];
  E0bp[idx] = f2bf(sec ? -v : v);
}

// E0Tbp: sections ch [E0_re^T, -E0_im^T] (262144 shorts each). A-row = k(256), A-col = m(1024), KC=64.
__global__ void prep_pack_E0T(const float* __restrict__ E0, short* __restrict__ E0Tbp) {
  const int idx = blockIdx.x * 256 + threadIdx.x;   // 524288 threads
  const int ch = idx >> 18, r = idx & 262143;
  const int j = r & 7, l31 = (r >> 3) & 31, h = (r >> 8) & 1, kc = (r >> 9) & 63, rt = r >> 15;
  const int krow = rt * 32 + l31, mcol = kc * 16 + h * 8 + j;
  const float v = E0[ch * 262144 + mcol * 256 + krow];
  E0Tbp[idx] = f2bf(ch ? -v : v);
}

// ---------------- main fused kernel ----------------
// grid 256 (batch tile of 32), block 512 (8 waves; wave w = row-tile rt).
// LDS: buf0 (32KB) = x bf16 [ch][b=32][256] / aliased z chunk [b=32][512]
//      buf1 (32KB) = gx bf16 [ch][b=32][256]
//      bufy (12KB) = y bf16 [y0|y1|-y1][b=32][128]  (persistent)
// Total 88KB -> 1 block/CU.  All LDS rows XOR-swizzled at 16B granules.

__global__ __attribute__((amdgpu_flat_work_group_size(512, 512), amdgpu_waves_per_eu(2, 2)))
void ista_main(
    const float* __restrict__ y,
    const float* __restrict__ etas,
    const float* __restrict__ gammas,
    const short* __restrict__ Cbp,
    const short* __restrict__ WXbp,
    const short* __restrict__ E0bp,
    const short* __restrict__ E0Tbp,
    float* __restrict__ out) {
  __shared__ short buf0[16384];
  __shared__ short buf1[16384];
  __shared__ short bufy[12288];

  const int tid = threadIdx.x;
  const int w = tid >> 6;          // wave 0..7 == row-tile
  const int lane = tid & 63;
  const int l31 = lane & 31;
  const int h = lane >> 5;         // half-wave
  const int sw = l31 & 7;          // swizzle key
  const int b0 = blockIdx.x * 32;
  const int lq = l31 * 8;          // packed-fragment lane offset (shorts)

  // ---- stage y -> bufy: [0]=y_re, [1]=y_im, [2]=-y_im (bf16, swizzled rows of 128)
  {
    const int bt = tid >> 4, j = tid & 15;      // 16 threads per batch row
    const float* yb = y + (size_t)(b0 + bt) * 256;
    const int bsw = (bt & 7);
    #pragma unroll
    for (int rep = 0; rep < 2; rep++) {
      const int jj = j + rep * 16;
      const int ch = jj >> 4, n8 = (jj & 15) << 3;
      const float4 v0 = *(const float4*)(yb + ch * 128 + n8);
      const float4 v1 = *(const float4*)(yb + ch * 128 + n8 + 4);
      s8v pk;
      pk[0] = f2bf(v0.x); pk[1] = f2bf(v0.y); pk[2] = f2bf(v0.z); pk[3] = f2bf(v0.w);
      pk[4] = f2bf(v1.x); pk[5] = f2bf(v1.y); pk[6] = f2bf(v1.z); pk[7] = f2bf(v1.w);
      const int off = bt * 128 + (((n8 >> 3) ^ bsw) << 3);
      *(s8v*)(bufy + ch * 4096 + off) = pk;
      if (ch == 1) {
        s8v nk;
        #pragma unroll
        for (int e = 0; e < 8; e++) nk[e] = pk[e] ^ (short)0x8000;
        *(s8v*)(bufy + 8192 + off) = nk;
      }
    }
  }
  // ---- zero buf0 (x = 0): 512 threads x 32 shorts
  {
    s8v z = {0, 0, 0, 0, 0, 0, 0, 0};
    #pragma unroll
    for (int r = 0; r < 4; r++) *(s8v*)(buf0 + tid * 32 + r * 8) = z;
  }
  __syncthreads();

  float ls = 0.f, leq = 0.f, cntf = 0.f;
  f16v xm0, xm1;
  #pragma unroll
  for (int r = 0; r < 16; r++) { xm0[r] = 0.f; xm1[r] = 0.f; }

  #pragma unroll 1
  for (int it = 1; it <= 10; it++) {
    const float gam = gammas[it];
    const float eta = etas[it];

    // ---- Phase A: ac = C*x - d~ ; gx = x - gam*ac   (both channels per wave)
    f16v ac0, ac1;
    #pragma unroll
    for (int r = 0; r < 16; r++) { ac0[r] = 0.f; ac1[r] = 0.f; }
    #pragma unroll
    for (int kc = 0; kc < 8; kc++) {       // -d~ = (-WX) * y
      const int pa = ((w * 8 + kc) * 2 + h) * 256 + lq;
      const s8v a0 = *(const s8v*)(WXbp + pa);            // -WX0
      const s8v a1 = *(const s8v*)(WXbp + 32768 + pa);    // -WX1
      const int yo = l31 * 128 + ((((kc * 2 + h)) ^ sw) << 3);
      const s8v by0 = *(const s8v*)(bufy + yo);           // y0
      const s8v by1 = *(const s8v*)(bufy + 4096 + yo);    // y1
      const s8v by1n = *(const s8v*)(bufy + 8192 + yo);   // -y1
      ac0 = MFMA(a0, by0, ac0);
      ac0 = MFMA(a1, by1n, ac0);
      ac1 = MFMA(a0, by1, ac1);
      ac1 = MFMA(a1, by0, ac1);
    }
    #pragma unroll
    for (int kc = 0; kc < 16; kc++) {      // + C * x
      const int pa = ((w * 16 + kc) * 2 + h) * 256 + lq;
      const s8v a0 = *(const s8v*)(Cbp + pa);             // C0
      const s8v a1 = *(const s8v*)(Cbp + 65536 + pa);     // C1
      const s8v a1n = *(const s8v*)(Cbp + 131072 + pa);   // -C1
      const int xo = l31 * 256 + ((((kc * 2 + h)) ^ sw) << 3);
      const s8v bx0 = *(const s8v*)(buf0 + xo);
      const s8v bx1 = *(const s8v*)(buf0 + 8192 + xo);
      ac0 = MFMA(a0, bx0, ac0);
      ac0 = MFMA(a1n, bx1, ac0);
      ac1 = MFMA(a0, bx1, ac1);
      ac1 = MFMA(a1, bx0, ac1);
    }
    // gx = x - gam*ac  (x read per-lane from LDS bf16); write gx bf16 -> buf1
    #pragma unroll
    for (int r1 = 0; r1 < 4; r1++) {
      const int k0 = w * 32 + 8 * r1 + 4 * h;
      const int idx = l31 * 256 + (((k0 >> 3) ^ sw) << 3) + (k0 & 7);
      const s4v xv0 = *(const s4v*)(buf0 + idx);
      const s4v xv1 = *(const s4v*)(buf0 + 8192 + idx);
      s4v p0, p1;
      #pragma unroll
      for (int r0 = 0; r0 < 4; r0++) {
        p0[r0] = f2bf(bf2f(xv0[r0]) - gam * ac0[r1 * 4 + r0]);
        p1[r0] = f2bf(bf2f(xv1[r0]) - gam * ac1[r1 * 4 + r0]);
      }
      *(s4v*)(buf1 + idx) = p0;
      *(s4v*)(buf1 + 8192 + idx) = p1;
    }
    __syncthreads();

    #pragma unroll
    for (int r = 0; r < 16; r++) { xm0[r] = 0.f; xm1[r] = 0.f; }

    #pragma unroll 1
    for (int c = 0; c < 2; c++) {
      // ---- Phase B: z = Re(E0 * gx); 2 m-tiles per wave (mt, mt+8)
      f16v z1, z2;
      #pragma unroll
      for (int r = 0; r < 16; r++) { z1[r] = 0.f; z2[r] = 0.f; }
      {
        const int mt1 = c * 16 + w, mt2 = mt1 + 8;
        #pragma unroll
        for (int kc = 0; kc < 16; kc++) {
          const int pa1 = ((mt1 * 16 + kc) * 2 + h) * 256 + lq;
          const int pa2 = ((mt2 * 16 + kc) * 2 + h) * 256 + lq;
          const s8v aE01 = *(const s8v*)(E0bp + pa1);
          const s8v aE11 = *(const s8v*)(E0bp + 262144 + pa1);
          const s8v aE02 = *(const s8v*)(E0bp + pa2);
          const s8v aE12 = *(const s8v*)(E0bp + 262144 + pa2);
          const int xo = l31 * 256 + ((((kc * 2 + h)) ^ sw) << 3);
          const s8v bg0 = *(const s8v*)(buf1 + xo);
          const s8v bg1 = *(const s8v*)(buf1 + 8192 + xo);
          z1 = MFMA(aE01, bg0, z1);
          z1 = MFMA(aE11, bg1, z1);
          z2 = MFMA(aE02, bg0, z2);
          z2 = MFMA(aE12, bg1, z2);
        }
      }
      // shrink + losses + write z chunk -> buf0 [b=32][512]
      #pragma unroll
      for (int half = 0; half < 2; half++) {
        const int mtl = half * 8 + w;
        #pragma unroll
        for (int r1 = 0; r1 < 4; r1++) {
          s4v ps;
          #pragma unroll
          for (int r0 = 0; r0 < 4; r0++) {
            const float v = half ? z2[r1 * 4 + r0] : z1[r1 * 4 + r0];
            const float av = fabsf(v) - eta;
            float s = 0.f;
            if (av > 0.f) {
              s = (v > 0.f) ? av : -av;
              ls += av;
              if (it == 10 && av > 1e-3f) cntf += 1.f;
            }
            ps[r0] = f2bf(s);
          }
          const int ml = mtl * 32 + 8 * r1 + 4 * h;
          *(s4v*)(buf0 + l31 * 512 + (((ml >> 3) ^ sw) << 3) + (ml & 7)) = ps;
        }
      }
      __syncthreads();

      // ---- Phase C: xm += [E0_re^T; -E0_im^T] * s  (reduce over chunk's 512 m)
      {
        #pragma unroll
        for (int kc = 0; kc < 32; kc++) {
          const int pa = ((w * 64 + c * 32 + kc) * 2 + h) * 256 + lq;
          const s8v aT0 = *(const s8v*)(E0Tbp + pa);
          const s8v aT1 = *(const s8v*)(E0Tbp + 262144 + pa);
          const int zo = l31 * 512 + ((((kc * 2 + h)) ^ sw) << 3);
          const s8v bz = *(const s8v*)(buf0 + zo);
          xm0 = MFMA(aT0, bz, xm0);
          xm1 = MFMA(aT1, bz, xm1);
        }
      }
      __syncthreads();
    }

    // ---- Phase D: huber(gx, xm); x = xm (bf16) -> buf0
    #pragma unroll
    for (int r1 = 0; r1 < 4; r1++) {
      const int k0 = w * 32 + 8 * r1 + 4 * h;
      const int idx = l31 * 256 + (((k0 >> 3) ^ sw) << 3) + (k0 & 7);
      const s4v gv0 = *(const s4v*)(buf1 + idx);
      const s4v gv1 = *(const s4v*)(buf1 + 8192 + idx);
      s4v p0, p1;
      #pragma unroll
      for (int r0 = 0; r0 < 4; r0++) {
        const float x0 = xm0[r1 * 4 + r0], x1 = xm1[r1 * 4 + r0];
        const float d0 = bf2f(gv0[r0]) - x0;
        const float d1 = bf2f(gv1[r0]) - x1;
        const float a0 = fabsf(d0), a1 = fabsf(d1);
        leq += (a0 < 1.f) ? 0.5f * d0 * d0 : (a0 - 0.5f);
        leq += (a1 < 1.f) ? 0.5f * d1 * d1 : (a1 - 0.5f);
        p0[r0] = f2bf(x0);
        p1[r0] = f2bf(x1);
      }
      *(s4v*)(buf0 + idx) = p0;
      *(s4v*)(buf0 + 8192 + idx) = p1;
    }
    __syncthreads();
  }

  // ---- write x_T (2, 8192, 256) fp32 from final xm (both channels)
  {
    const size_t ob = (size_t)(b0 + l31) * 256;
    #pragma unroll
    for (int r1 = 0; r1 < 4; r1++) {
      const int k0 = w * 32 + 8 * r1 + 4 * h;
      float4 v0, v1;
      v0.x = xm0[r1 * 4 + 0]; v0.y = xm0[r1 * 4 + 1]; v0.z = xm0[r1 * 4 + 2]; v0.w = xm0[r1 * 4 + 3];
      v1.x = xm1[r1 * 4 + 0]; v1.y = xm1[r1 * 4 + 1]; v1.z = xm1[r1 * 4 + 2]; v1.w = xm1[r1 * 4 + 3];
      *(float4*)(out + ob + k0) = v0;
      *(float4*)(out + 2097152 + ob + k0) = v1;
    }
  }
  // ---- scalar reductions
  #pragma unroll
  for (int off = 32; off > 0; off >>= 1) {
    ls += __shfl_down(ls, off);
    leq += __shfl_down(leq, off);
    cntf += __shfl_down(cntf, off);
  }
  if (lane == 0) {
    atomicAdd(out + 4194304, ls * (1.f / 8192.f));
    atomicAdd(out + 4194305, leq * (1.f / (2.f * 256.f * 8192.f * 10.f)));
    atomicAdd(out + 4194306, cntf * (1.f / 8192.f));
  }
}

extern "C" void kernel_launch(void* const* d_in, const int* in_sizes, int n_in,
                              void* d_out, int out_size, void* d_ws, size_t ws_size,
                              hipStream_t stream) {
  (void)in_sizes; (void)n_in; (void)out_size; (void)ws_size;
  const float* y = (const float*)d_in[0];
  const float* W = (const float*)d_in[1];
  const float* WX = (const float*)d_in[2];
  const float* E0 = (const float*)d_in[3];
  const float* etas = (const float*)d_in[4];
  const float* gammas = (const float*)d_in[5];
  float* out = (float*)d_out;

  short* Cbp = (short*)d_ws;           // 3 * 65536
  short* WXbp = Cbp + 196608;          // 2 * 32768
  short* E0bp = WXbp + 65536;          // 2 * 262144
  short* E0Tbp = E0bp + 524288;        // 2 * 262144  (total ~2.6 MB)

  zero_tail<<<1, 64, 0, stream>>>(out);
  prep_pack_C<<<768, 256, 0, stream>>>(W, WX, Cbp);
  prep_pack_WX<<<256, 256, 0, stream>>>(WX, WXbp);
  prep_pack_E0<<<2048, 256, 0, stream>>>(E0, E0bp);
  prep_pack_E0T<<<2048, 256, 0, stream>>>(E0, E0Tbp);
  ista_main<<<256, 512, 0, stream>>>(y, etas, gammas, Cbp, WXbp, E0bp, E0Tbp, out);
}